// Round 17
// baseline (98.645 us; speedup 1.0000x reference)
//
#include <hip/hip_runtime.h>

#define DM 96
#define NH 4
#define DH 24
#define CAP 64            // per-node bucket capacity; deg ~ Poisson(16)
#define BSH 8             // 256 nodes per coarse bin
#define BCAP2 5120        // records per coarse bin; lambda ~4082, +16 sigma
#define ECHUNK 3072       // edges per scat block (12 per thread)
#define SWP 104           // LDS W-tile row stride (shorts): 16B-aligned, 8/bank uniform

typedef __attribute__((ext_vector_type(8))) __bf16 bf16x8;
typedef __attribute__((ext_vector_type(4))) float f32x4;

__device__ inline unsigned short f2bf(float f) {            // RNE f32->bf16
    union { float f; unsigned int i; } c; c.f = f;
    unsigned int r = c.i + 0x7FFFu + ((c.i >> 16) & 1u);
    return (unsigned short)(r >> 16);
}
__device__ inline float lo_bf(unsigned int u) { union { unsigned int i; float f; } c; c.i = u << 16; return c.f; }
__device__ inline float hi_bf(unsigned int u) { union { unsigned int i; float f; } c; c.i = u & 0xFFFF0000u; return c.f; }

// ---------- merged: scat blocks [0, nscat) + proj blocks [nscat, nscat+nproj) ----------
// Both depend only on kernel inputs (proj stages W into LDS itself -> no WT buffer,
// no scat->proj dependency). scat first so csr's dependency completes earliest.
__global__ __launch_bounds__(256) void projscat_kernel(
    const float* __restrict__ emb,
    const float* __restrict__ qW, const float* __restrict__ kW, const float* __restrict__ vW,
    const int* __restrict__ rows, const int* __restrict__ cols,
    unsigned short* __restrict__ Qb, unsigned short* __restrict__ KVb,
    int* __restrict__ gbcnt, uint2* __restrict__ bbuf,
    int n, int e, int nbin, int nscat)
{
    __shared__ __align__(16) unsigned char smem[27712];

    if ((int)blockIdx.x < nscat) {
        // ---- scat: LDS counting-sort edge scatter into coarse bins ----
        int* cnt0  = (int*)smem;              // 256
        int* excl  = cnt0 + 256;              // 256
        int* gbase = excl + 256;              // 256
        int* wsum  = gbase + 256;             // 16 (4 used)
        uint2* stage = (uint2*)(smem + 3136); // ECHUNK records, 24 KB

        int t = threadIdx.x;
        cnt0[t] = 0;
        __syncthreads();

        int base = blockIdx.x * ECHUNK;
        int r[12], c[12], lp[12];
        #pragma unroll
        for (int i = 0; i < 12; ++i) {
            int idx = base + i * 256 + t;          // coalesced
            bool ok = idx < e;
            r[i] = ok ? rows[idx] : -1;
            c[i] = ok ? cols[idx] : 0;
            if (ok) lp[i] = atomicAdd(&cnt0[r[i] >> BSH], 1);
        }
        __syncthreads();

        // exclusive scan of cnt0[256] via wave-shfl scan
        int v = cnt0[t];
        int lane = t & 63, wv = t >> 6;
        int x = v;
        #pragma unroll
        for (int o = 1; o < 64; o <<= 1) {
            int y = __shfl_up(x, o);
            if (lane >= o) x += y;
        }
        if (lane == 63) wsum[wv] = x;
        __syncthreads();
        int wbase = 0;
        #pragma unroll
        for (int i = 0; i < 4; ++i) if (i < wv) wbase += wsum[i];
        int ex = x + wbase - v;
        int total = wsum[0] + wsum[1] + wsum[2] + wsum[3];
        excl[t] = ex;
        if (t < nbin && v > 0) gbase[t] = atomicAdd(&gbcnt[t], v);
        __syncthreads();

        #pragma unroll
        for (int i = 0; i < 12; ++i) {
            if (r[i] >= 0) {
                int b = r[i] >> BSH;
                stage[excl[b] + lp[i]] = make_uint2((unsigned)r[i], (unsigned)c[i]);
            }
        }
        __syncthreads();

        for (int j = t; j < total; j += 256) {
            uint2 rc = stage[j];
            int b = rc.x >> BSH;
            int pos = gbase[b] + (j - excl[b]);
            if (pos < BCAP2) bbuf[(size_t)b * BCAP2 + pos] = rc;
        }
    } else {
        // ---- projection: Qb (bf16), KVb (bf16 K|V interleaved) ----
        // W staged per-mat into LDS as bf16 transposed [c][k], stride SWP.
        unsigned short* sW = (unsigned short*)smem;   // 96*SWP shorts = 19.9 KB

        int tile = blockIdx.x - nscat;
        int l = threadIdx.x & 63;
        int w = threadIdx.x >> 6;
        int row0 = tile * 64 + w * 16;
        int lr = l & 15;     // A row / B col / C col
        int lk = l >> 4;     // k-chunk 0..3
        int arow = row0 + lr; if (arow >= n) arow = n - 1;

        bf16x8 a[3];
        {
            const float4* e4p = (const float4*)(emb + (size_t)arow * DM);
            #pragma unroll
            for (int kb = 0; kb < 3; ++kb) {
                float4 f0 = e4p[kb * 8 + lk * 2];
                float4 f1 = e4p[kb * 8 + lk * 2 + 1];
                union { unsigned short u[8]; bf16x8 b; } cv;
                cv.u[0] = f2bf(f0.x); cv.u[1] = f2bf(f0.y); cv.u[2] = f2bf(f0.z); cv.u[3] = f2bf(f0.w);
                cv.u[4] = f2bf(f1.x); cv.u[5] = f2bf(f1.y); cv.u[6] = f2bf(f1.z); cv.u[7] = f2bf(f1.w);
                a[kb] = cv.b;
            }
        }

        for (int mat = 0; mat < 3; ++mat) {
            const float* W = (mat == 0) ? qW : (mat == 1) ? kW : vW;
            __syncthreads();   // previous mat's LDS reads done before overwrite
            // stage W -> sW[c][k] (bf16): 2304 float4s, 9 per thread
            for (int i4 = threadIdx.x; i4 < (DM * DM) / 4; i4 += 256) {
                int i = i4 * 4;                    // k = i/96, c = i%96 (multiple of 4)
                int k = i / DM, cc = i - k * DM;
                float4 v = *(const float4*)(W + i);
                sW[(cc + 0) * SWP + k] = f2bf(v.x);
                sW[(cc + 1) * SWP + k] = f2bf(v.y);
                sW[(cc + 2) * SWP + k] = f2bf(v.z);
                sW[(cc + 3) * SWP + k] = f2bf(v.w);
            }
            __syncthreads();

            f32x4 acc[6];
            #pragma unroll
            for (int tc = 0; tc < 6; ++tc) acc[tc] = (f32x4){0.f, 0.f, 0.f, 0.f};
            #pragma unroll
            for (int kb = 0; kb < 3; ++kb) {
                #pragma unroll
                for (int tc = 0; tc < 6; ++tc) {
                    union { uint4 u; bf16x8 b; } bv;
                    bv.u = *(const uint4*)&sW[(size_t)(tc * 16 + lr) * SWP + kb * 32 + lk * 8];
                    acc[tc] = __builtin_amdgcn_mfma_f32_16x16x32_bf16(a[kb], bv.b, acc[tc], 0, 0, 0);
                }
            }
            #pragma unroll
            for (int tc = 0; tc < 6; ++tc) {
                #pragma unroll
                for (int r = 0; r < 4; ++r) {
                    int grow = row0 + lk * 4 + r;    // C/D: row=(l>>4)*4+reg, col=l&15
                    if (grow < n) {
                        if (mat == 0)
                            Qb[(size_t)grow * DM + tc * 16 + lr] = f2bf(acc[tc][r]);
                        else
                            KVb[(size_t)grow * (2 * DM) + (mat - 1) * DM + tc * 16 + lr] = f2bf(acc[tc][r]);
                    }
                }
            }
        }
    }
}

// ---------- csr: per-bin re-scatter into per-node buckets (LDS counters) ----------
__global__ __launch_bounds__(256) void csr_kernel(
    const int* __restrict__ gbcnt, const uint2* __restrict__ bbuf,
    int* __restrict__ cnt, int* __restrict__ pcols, int n)
{
    __shared__ int lcnt[256];
    int b = blockIdx.x;
    int t = threadIdx.x;
    lcnt[t] = 0;
    __syncthreads();
    int m = gbcnt[b]; if (m > BCAP2) m = BCAP2;
    const uint2* src = bbuf + (size_t)b * BCAP2;
    int nbase = b << BSH;
    for (int i = t; i < m; i += 256) {
        uint2 rc = src[i];
        int pos = atomicAdd(&lcnt[(int)rc.x - nbase], 1);
        if (pos < CAP) pcols[(size_t)rc.x * CAP + pos] = (int)rc.y;
    }
    __syncthreads();
    int node = nbase + t;
    if (node < n) cnt[node] = lcnt[t];
}

// ---------- fused attention: 2 nodes/wave, 8-way split x 4 heads, register buckets ----------
// lane l: nd = l>>5, s = (l>>2)&7, h = l&3. All shfls run with 64 lanes in lockstep:
// wave-uniform nit; memory/compute body predicated on j < count.
#define RED3(x) { x += __shfl_xor(x, 4); x += __shfl_xor(x, 8); x += __shfl_xor(x, 16); }

__global__ __launch_bounds__(256) void node_kernel(
    const float* __restrict__ emb, const unsigned short* __restrict__ Qb,
    const unsigned short* __restrict__ KVb,
    const int* __restrict__ cnt, const int* __restrict__ pcols,
    float* __restrict__ out, int n)
{
    int wv = (blockIdx.x * 256 + threadIdx.x) >> 6;   // global wave id
    int l = threadIdx.x & 63;
    int s  = (l >> 2) & 7;    // 0..7
    int h  = l & 3;           // head
    int node = wv * 2 + (l >> 5);
    bool valid = node < n;
    int nodec = valid ? node : n - 1;

    int count = cnt[nodec];
    if (count > CAP) count = CAP;
    if (!valid) count = 0;

    int maxc = count;
    maxc = max(maxc, __shfl_xor(maxc, 32));
    int nit = (maxc + 7) >> 3;           // wave-uniform iteration count

    // register bucket: lane l holds slot (l&31) of its node — covers slots 0..31
    int bb = pcols[(size_t)nodec * CAP + (l & 31)];

    // Q: head h slice, bf16 -> f32 registers
    float q[24];
    {
        const uint4* q4 = (const uint4*)(Qb + (size_t)nodec * DM + h * DH);
        #pragma unroll
        for (int t = 0; t < 3; ++t) {
            uint4 u = q4[t];
            unsigned int uw[4] = {u.x, u.y, u.z, u.w};
            #pragma unroll
            for (int j2 = 0; j2 < 4; ++j2) {
                q[t * 8 + j2 * 2]     = lo_bf(uw[j2]);
                q[t * 8 + j2 * 2 + 1] = hi_bf(uw[j2]);
            }
        }
    }

    float a[24];
    #pragma unroll
    for (int i = 0; i < 24; ++i) a[i] = 0.f;
    float denom = 0.f;

    for (int it = 0; it < nit; ++it) {
        int j = it * 8 + s;
        int c = __shfl(bb, (l & 32) + (j & 31));                        // lockstep shfl
        if (j >= 32 && j < count) c = pcols[(size_t)node * CAP + j];    // tail (deg > 32), rare

        if (j < count) {
            const uint4* kp = (const uint4*)(KVb + (size_t)c * (2 * DM) + h * DH);
            uint4 ku[3] = {kp[0], kp[1], kp[2]};        // K slice
            uint4 vu[3] = {kp[12], kp[13], kp[14]};     // V slice (+96 shorts = +12 uint4)

            float dot = 0.f;
            #pragma unroll
            for (int t = 0; t < 3; ++t) {
                unsigned int uw[4] = {ku[t].x, ku[t].y, ku[t].z, ku[t].w};
                #pragma unroll
                for (int j2 = 0; j2 < 4; ++j2)
                    dot += lo_bf(uw[j2]) * q[t * 8 + j2 * 2] + hi_bf(uw[j2]) * q[t * 8 + j2 * 2 + 1];
            }
            dot = fminf(fmaxf(dot, -10.f), 10.f);
            float es = __expf(dot);
            denom += es;
            #pragma unroll
            for (int t = 0; t < 3; ++t) {
                unsigned int uw[4] = {vu[t].x, vu[t].y, vu[t].z, vu[t].w};
                #pragma unroll
                for (int j2 = 0; j2 < 4; ++j2) {
                    a[t * 8 + j2 * 2]     += es * lo_bf(uw[j2]);
                    a[t * 8 + j2 * 2 + 1] += es * hi_bf(uw[j2]);
                }
            }
        }
    }

    RED3(denom)
    #pragma unroll
    for (int i = 0; i < 24; ++i) { RED3(a[i]) }

    if (s == 0 && valid) {
        float sc = 1.f / (denom + 1e-8f);
        const f32x4* e4 = (const f32x4*)(emb + (size_t)node * DM + h * DH);
        f32x4* o4 = (f32x4*)(out + (size_t)node * DM + h * DH);
        #pragma unroll
        for (int t = 0; t < 6; ++t) {
            f32x4 ev = e4[t];
            f32x4 ov;
            ov.x = ev.x + a[t * 4 + 0] * sc;
            ov.y = ev.y + a[t * 4 + 1] * sc;
            ov.z = ev.z + a[t * 4 + 2] * sc;
            ov.w = ev.w + a[t * 4 + 3] * sc;
            o4[t] = ov;
        }
    }
}

extern "C" void kernel_launch(void* const* d_in, const int* in_sizes, int n_in,
                              void* d_out, int out_size, void* d_ws, size_t ws_size,
                              hipStream_t stream) {
    const float* emb = (const float*)d_in[0];
    const float* qW  = (const float*)d_in[1];
    const float* kW  = (const float*)d_in[2];
    const float* vW  = (const float*)d_in[3];
    const int* rows  = (const int*)d_in[4];
    const int* cols  = (const int*)d_in[5];
    float* out = (float*)d_out;

    int n = in_sizes[0] / DM;     // 50000
    int e = in_sizes[4];          // 800000
    int nbin = (n + (1 << BSH) - 1) >> BSH;        // 196

    unsigned short* KVb = (unsigned short*)d_ws;         // n*192 bf16  (19.2 MB)
    unsigned short* Qb  = KVb + (size_t)n * 2 * DM;      // n*96 bf16   (9.6 MB)
    int* cnt   = (int*)(Qb + (size_t)n * DM);            // n           (0.2 MB)
    int* gbcnt = cnt + n;                                // nbin
    int* pcols = gbcnt + nbin;                           // n*CAP       (12.8 MB)
    uint2* bbuf = (uint2*)(pcols + (size_t)n * CAP);     // nbin*BCAP2  (8.0 MB)

    hipMemsetAsync(gbcnt, 0, (size_t)nbin * sizeof(int), stream);

    int nscat = (e + ECHUNK - 1) / ECHUNK;               // 261
    int nproj = (n + 63) / 64;                           // 782
    projscat_kernel<<<nscat + nproj, 256, 0, stream>>>(emb, qW, kW, vW, rows, cols,
                                                       Qb, KVb, gbcnt, bbuf,
                                                       n, e, nbin, nscat);

    csr_kernel<<<nbin, 256, 0, stream>>>(gbcnt, bbuf, cnt, pcols, n);

    node_kernel<<<(n + 7) / 8, 256, 0, stream>>>(emb, Qb, KVb, cnt, pcols, out, n);
}

// Round 18
// 91.924 us; speedup vs baseline: 1.0731x; 1.0731x over previous
//
#include <hip/hip_runtime.h>

#define DM 96
#define NH 4
#define DH 24
#define CAP 64            // per-node bucket capacity; deg ~ Poisson(16)
#define BSH 8             // 256 nodes per coarse bin
#define BCAP2 5120        // records per coarse bin; lambda ~4082, +16 sigma
#define ECHUNK 3072       // edges per scat block (12 per thread)

typedef __attribute__((ext_vector_type(8))) __bf16 bf16x8;
typedef __attribute__((ext_vector_type(4))) float f32x4;

__device__ inline unsigned short f2bf(float f) {            // RNE f32->bf16
    union { float f; unsigned int i; } c; c.f = f;
    unsigned int r = c.i + 0x7FFFu + ((c.i >> 16) & 1u);
    return (unsigned short)(r >> 16);
}
__device__ inline float lo_bf(unsigned int u) { union { unsigned int i; float f; } c; c.i = u << 16; return c.f; }
__device__ inline float hi_bf(unsigned int u) { union { unsigned int i; float f; } c; c.i = u & 0xFFFF0000u; return c.f; }

// ---------- scat: WT build + LDS counting-sort edge scatter into coarse bins ----------
__global__ __launch_bounds__(256) void scat_kernel(
    const float* __restrict__ qW, const float* __restrict__ kW, const float* __restrict__ vW,
    const int* __restrict__ rows, const int* __restrict__ cols,
    unsigned short* __restrict__ WT,
    int* __restrict__ gbcnt, uint2* __restrict__ bbuf, int e, int nbin)
{
    __shared__ int cnt0[256];
    __shared__ int excl[256];
    __shared__ int gbase[256];
    __shared__ int wsum[4];
    __shared__ uint2 stage[ECHUNK];   // 24 KB

    int t = threadIdx.x;

    int gtid = blockIdx.x * 256 + t;
    if (gtid < 3 * DM * DM) {
        int mat = gtid / (DM * DM);
        int rr = gtid - mat * (DM * DM);
        int c = rr / DM, k = rr - c * DM;
        const float* W = (mat == 0) ? qW : (mat == 1) ? kW : vW;
        WT[gtid] = f2bf(W[k * DM + c]);
    }

    cnt0[t] = 0;
    __syncthreads();

    int base = blockIdx.x * ECHUNK;
    int r[12], c[12], lp[12];
    #pragma unroll
    for (int i = 0; i < 12; ++i) {
        int idx = base + i * 256 + t;          // coalesced
        bool ok = idx < e;
        r[i] = ok ? rows[idx] : -1;
        c[i] = ok ? cols[idx] : 0;
        if (ok) lp[i] = atomicAdd(&cnt0[r[i] >> BSH], 1);
    }
    __syncthreads();

    // exclusive scan of cnt0[256] via wave-shfl scan (2 barriers)
    int v = cnt0[t];
    int lane = t & 63, w = t >> 6;
    int x = v;
    #pragma unroll
    for (int o = 1; o < 64; o <<= 1) {
        int y = __shfl_up(x, o);
        if (lane >= o) x += y;
    }
    if (lane == 63) wsum[w] = x;
    __syncthreads();
    int wbase = 0;
    #pragma unroll
    for (int i = 0; i < 4; ++i) if (i < w) wbase += wsum[i];
    int ex = x + wbase - v;
    int total = wsum[0] + wsum[1] + wsum[2] + wsum[3];
    excl[t] = ex;
    if (t < nbin && v > 0) gbase[t] = atomicAdd(&gbcnt[t], v);
    __syncthreads();

    #pragma unroll
    for (int i = 0; i < 12; ++i) {
        if (r[i] >= 0) {
            int b = r[i] >> BSH;
            stage[excl[b] + lp[i]] = make_uint2((unsigned)r[i], (unsigned)c[i]);
        }
    }
    __syncthreads();

    for (int j = t; j < total; j += 256) {
        uint2 rc = stage[j];
        int b = rc.x >> BSH;
        int pos = gbase[b] + (j - excl[b]);
        if (pos < BCAP2) bbuf[(size_t)b * BCAP2 + pos] = rc;
    }
}

// ---------- merged: proj blocks [0, nproj) + csr blocks [nproj, nproj+nbin) ----------
__global__ __launch_bounds__(256) void csrproj_kernel(
    const float* __restrict__ emb, const unsigned short* __restrict__ WT,
    unsigned short* __restrict__ Qb, unsigned short* __restrict__ KVb,
    const int* __restrict__ gbcnt, const uint2* __restrict__ bbuf,
    int* __restrict__ cnt, int* __restrict__ pcols, int n, int nproj)
{
    if ((int)blockIdx.x < nproj) {
        // ---- projection: Qb (bf16), KVb (bf16 K|V interleaved); emb->bf16 on the fly ----
        int l = threadIdx.x & 63;
        int w = threadIdx.x >> 6;
        int row0 = blockIdx.x * 64 + w * 16;
        int lr = l & 15;     // A row / B col / C col
        int lk = l >> 4;     // k-chunk 0..3
        int arow = row0 + lr; if (arow >= n) arow = n - 1;

        bf16x8 a[3];
        {
            const float4* e4p = (const float4*)(emb + (size_t)arow * DM);
            #pragma unroll
            for (int kb = 0; kb < 3; ++kb) {
                float4 f0 = e4p[kb * 8 + lk * 2];
                float4 f1 = e4p[kb * 8 + lk * 2 + 1];
                union { unsigned short u[8]; bf16x8 b; } cv;
                cv.u[0] = f2bf(f0.x); cv.u[1] = f2bf(f0.y); cv.u[2] = f2bf(f0.z); cv.u[3] = f2bf(f0.w);
                cv.u[4] = f2bf(f1.x); cv.u[5] = f2bf(f1.y); cv.u[6] = f2bf(f1.z); cv.u[7] = f2bf(f1.w);
                a[kb] = cv.b;
            }
        }

        for (int mat = 0; mat < 3; ++mat) {
            const unsigned short* Wm = WT + mat * DM * DM;
            f32x4 acc[6];
            #pragma unroll
            for (int tc = 0; tc < 6; ++tc) acc[tc] = (f32x4){0.f, 0.f, 0.f, 0.f};
            #pragma unroll
            for (int kb = 0; kb < 3; ++kb) {
                #pragma unroll
                for (int tc = 0; tc < 6; ++tc) {
                    union { uint4 u; bf16x8 b; } bv;
                    bv.u = *(const uint4*)&Wm[(size_t)(tc * 16 + lr) * DM + kb * 32 + lk * 8];
                    acc[tc] = __builtin_amdgcn_mfma_f32_16x16x32_bf16(a[kb], bv.b, acc[tc], 0, 0, 0);
                }
            }
            #pragma unroll
            for (int tc = 0; tc < 6; ++tc) {
                #pragma unroll
                for (int r = 0; r < 4; ++r) {
                    int grow = row0 + lk * 4 + r;    // C/D: row=(l>>4)*4+reg, col=l&15
                    if (grow < n) {
                        if (mat == 0)
                            Qb[(size_t)grow * DM + tc * 16 + lr] = f2bf(acc[tc][r]);
                        else
                            KVb[(size_t)grow * (2 * DM) + (mat - 1) * DM + tc * 16 + lr] = f2bf(acc[tc][r]);
                    }
                }
            }
        }
    } else {
        // ---- csr: per-bin re-scatter into per-node buckets (LDS counters) ----
        __shared__ int lcnt[256];
        int b = blockIdx.x - nproj;
        int t = threadIdx.x;
        lcnt[t] = 0;
        __syncthreads();
        int m = gbcnt[b]; if (m > BCAP2) m = BCAP2;
        const uint2* src = bbuf + (size_t)b * BCAP2;
        int nbase = b << BSH;
        for (int i = t; i < m; i += 256) {
            uint2 rc = src[i];
            int pos = atomicAdd(&lcnt[(int)rc.x - nbase], 1);
            if (pos < CAP) pcols[(size_t)rc.x * CAP + pos] = (int)rc.y;
        }
        __syncthreads();
        int node = nbase + t;
        if (node < n) cnt[node] = lcnt[t];
    }
}

// ---------- fused attention: 2 nodes/wave, 8-way split x 4 heads, register buckets ----------
// lane l: nd = l>>5, s = (l>>2)&7, h = l&3. All shfls run with 64 lanes in lockstep:
// wave-uniform nit; memory/compute body predicated on j < count.
#define RED3(x) { x += __shfl_xor(x, 4); x += __shfl_xor(x, 8); x += __shfl_xor(x, 16); }

__global__ __launch_bounds__(256) void node_kernel(
    const float* __restrict__ emb, const unsigned short* __restrict__ Qb,
    const unsigned short* __restrict__ KVb,
    const int* __restrict__ cnt, const int* __restrict__ pcols,
    float* __restrict__ out, int n)
{
    int wv = (blockIdx.x * 256 + threadIdx.x) >> 6;   // global wave id
    int l = threadIdx.x & 63;
    int s  = (l >> 2) & 7;    // 0..7
    int h  = l & 3;           // head
    int node = wv * 2 + (l >> 5);
    bool valid = node < n;
    int nodec = valid ? node : n - 1;

    int count = cnt[nodec];
    if (count > CAP) count = CAP;
    if (!valid) count = 0;

    int maxc = count;
    maxc = max(maxc, __shfl_xor(maxc, 32));
    int nit = (maxc + 7) >> 3;           // wave-uniform iteration count

    // register bucket: lane l holds slot (l&31) of its node — covers slots 0..31
    int bb = pcols[(size_t)nodec * CAP + (l & 31)];

    // Q: head h slice, bf16 -> f32 registers
    float q[24];
    {
        const uint4* q4 = (const uint4*)(Qb + (size_t)nodec * DM + h * DH);
        #pragma unroll
        for (int t = 0; t < 3; ++t) {
            uint4 u = q4[t];
            unsigned int uw[4] = {u.x, u.y, u.z, u.w};
            #pragma unroll
            for (int j2 = 0; j2 < 4; ++j2) {
                q[t * 8 + j2 * 2]     = lo_bf(uw[j2]);
                q[t * 8 + j2 * 2 + 1] = hi_bf(uw[j2]);
            }
        }
    }

    float a[24];
    #pragma unroll
    for (int i = 0; i < 24; ++i) a[i] = 0.f;
    float denom = 0.f;

    for (int it = 0; it < nit; ++it) {
        int j = it * 8 + s;
        int c = __shfl(bb, (l & 32) + (j & 31));                        // lockstep shfl
        if (j >= 32 && j < count) c = pcols[(size_t)node * CAP + j];    // tail (deg > 32), rare

        if (j < count) {
            const uint4* kp = (const uint4*)(KVb + (size_t)c * (2 * DM) + h * DH);
            uint4 ku[3] = {kp[0], kp[1], kp[2]};        // K slice
            uint4 vu[3] = {kp[12], kp[13], kp[14]};     // V slice (+96 shorts = +12 uint4)

            float dot = 0.f;
            #pragma unroll
            for (int t = 0; t < 3; ++t) {
                unsigned int uw[4] = {ku[t].x, ku[t].y, ku[t].z, ku[t].w};
                #pragma unroll
                for (int j2 = 0; j2 < 4; ++j2)
                    dot += lo_bf(uw[j2]) * q[t * 8 + j2 * 2] + hi_bf(uw[j2]) * q[t * 8 + j2 * 2 + 1];
            }
            dot = fminf(fmaxf(dot, -10.f), 10.f);
            float es = __expf(dot);
            denom += es;
            #pragma unroll
            for (int t = 0; t < 3; ++t) {
                unsigned int uw[4] = {vu[t].x, vu[t].y, vu[t].z, vu[t].w};
                #pragma unroll
                for (int j2 = 0; j2 < 4; ++j2) {
                    a[t * 8 + j2 * 2]     += es * lo_bf(uw[j2]);
                    a[t * 8 + j2 * 2 + 1] += es * hi_bf(uw[j2]);
                }
            }
        }
    }

    RED3(denom)
    #pragma unroll
    for (int i = 0; i < 24; ++i) { RED3(a[i]) }

    if (s == 0 && valid) {
        float sc = 1.f / (denom + 1e-8f);
        const f32x4* e4 = (const f32x4*)(emb + (size_t)node * DM + h * DH);
        f32x4* o4 = (f32x4*)(out + (size_t)node * DM + h * DH);
        #pragma unroll
        for (int t = 0; t < 6; ++t) {
            f32x4 ev = e4[t];
            f32x4 ov;
            ov.x = ev.x + a[t * 4 + 0] * sc;
            ov.y = ev.y + a[t * 4 + 1] * sc;
            ov.z = ev.z + a[t * 4 + 2] * sc;
            ov.w = ev.w + a[t * 4 + 3] * sc;
            o4[t] = ov;
        }
    }
}

extern "C" void kernel_launch(void* const* d_in, const int* in_sizes, int n_in,
                              void* d_out, int out_size, void* d_ws, size_t ws_size,
                              hipStream_t stream) {
    const float* emb = (const float*)d_in[0];
    const float* qW  = (const float*)d_in[1];
    const float* kW  = (const float*)d_in[2];
    const float* vW  = (const float*)d_in[3];
    const int* rows  = (const int*)d_in[4];
    const int* cols  = (const int*)d_in[5];
    float* out = (float*)d_out;

    int n = in_sizes[0] / DM;     // 50000
    int e = in_sizes[4];          // 800000
    int nbin = (n + (1 << BSH) - 1) >> BSH;        // 196

    // NO aliasing: csr (reads bbuf) and proj (writes Qb) run concurrently in one kernel.
    unsigned short* KVb = (unsigned short*)d_ws;         // n*192 bf16  (19.2 MB)
    unsigned short* WT  = KVb + (size_t)n * 2 * DM;      // 3*96*96 bf16 (55 KB)
    unsigned short* Qb  = WT + 3 * DM * DM;              // n*96 bf16   (9.6 MB)
    int* cnt   = (int*)(Qb + (size_t)n * DM);            // n           (0.2 MB)
    int* gbcnt = cnt + n;                                // nbin
    int* pcols = gbcnt + nbin;                           // n*CAP       (12.8 MB)
    uint2* bbuf = (uint2*)(pcols + (size_t)n * CAP);     // nbin*BCAP2  (8.0 MB)

    hipMemsetAsync(gbcnt, 0, (size_t)nbin * sizeof(int), stream);

    int nscat = (e + ECHUNK - 1) / ECHUNK;               // 261
    scat_kernel<<<nscat, 256, 0, stream>>>(qW, kW, vW, rows, cols, WT, gbcnt, bbuf, e, nbin);

    int nproj = (n + 63) / 64;                           // 782
    csrproj_kernel<<<nproj + nbin, 256, 0, stream>>>(emb, WT, Qb, KVb,
                                                     gbcnt, bbuf, cnt, pcols, n, nproj);

    node_kernel<<<(n + 7) / 8, 256, 0, stream>>>(emb, Qb, KVb, cnt, pcols, out, n);
}